// Round 1
// baseline (195.596 us; speedup 1.0000x reference)
//
#include <hip/hip_runtime.h>
#include <stdint.h>

// VectorQuantizer on MI355X (gfx950) — round 7
// inputs: x [64,256,32,32] fp32 (NCHW), codebook [1024,256] fp32
// outputs: q_st [64,256,32,32] fp32, loss scalar
//
// R7 restructure: 512 blocks x 128 hw rows; 4 waves x 32 rows, each wave sweeps
// ALL 32 m-tiles (1024 codes) in identical order -> A-stream dedup'd through L1
// (R6: nt-wave pairs duplicated A => 1 GB L2 traffic, latency exposed, VGPR=60
// showed the prefetch was compiler-defeated). B-frags hoisted to 64 VGPRs once
// (zero LDS reads in K-loop); A register-pipelined at 8-frag depth in two named
// buffers; acc split into two 8-deep MFMA chains; -0.5||c||^2 applied at scan.
// launch_bounds(256,2): ~200 VGPRs live, no spill. LDS 64.5 KB -> 2 blocks/CU.

#define DIM 256

typedef __attribute__((ext_vector_type(8)))  short bf16x8_t;   // MFMA A/B frag (4 VGPRs)
typedef __attribute__((ext_vector_type(4)))  float f32x4_t;
typedef __attribute__((ext_vector_type(16))) float f32x16_t;   // 32x32 C/D frag

__device__ __forceinline__ uint32_t f2bf(float f) {
    union { float f; uint32_t u; } v; v.f = f;
    uint32_t r = v.u + 0x7FFFu + ((v.u >> 16) & 1u);   // RNE
    return r >> 16;
}

// ---- prep: one wave per code. Emits (a) bf16 codebook in exact MFMA A-frag
// order: entry e=(mt*16+ks)*64+lane2 holds cb[mt*32+(lane2&31)][ks*16+(lane2>>5)*8+j],
// and (b) -0.5*||c||^2 in C/D-register order (nh_ord[mt*32 + half*16 + r]).
// Also zeroes loss_accum (replaces the hipMemsetAsync dispatch).
__global__ __launch_bounds__(256) void vq_prep(const float* __restrict__ cb,
                                               char* __restrict__ cbsw,
                                               float* __restrict__ nh_ord,
                                               float* __restrict__ loss_accum) {
    if (blockIdx.x == 0 && threadIdx.x == 0) *loss_accum = 0.f;

    const int code = blockIdx.x * 4 + (threadIdx.x >> 6);
    const int l    = threadIdx.x & 63;               // holds d = 4l..4l+3
    const f32x4_t v = ((const f32x4_t*)(cb + code * DIM))[l];
    float sq = v.x * v.x + v.y * v.y + v.z * v.z + v.w * v.w;

    const int mt = code >> 5;
    const int ks = l >> 2;               // d/16
    const int hl = (l >> 1) & 1;         // (d%16)/8
    const uint32_t ebyte = (uint32_t)(((mt * 16 + ks) * 64 + (code & 31) + 32 * hl) * 16
                                      + (l & 1) * 8);
    uint2 o;
    o.x = f2bf(v.x) | (f2bf(v.y) << 16);
    o.y = f2bf(v.z) | (f2bf(v.w) << 16);
    *(uint2*)(cbsw + ebyte) = o;

    #pragma unroll
    for (int m = 32; m; m >>= 1) sq += __shfl_xor(sq, m);
    if (l == 0) {
        const int rw = code & 31;
        const int h4 = (rw >> 2) & 1;
        const int r  = (rw & 3) | ((rw >> 3) << 2);
        nh_ord[mt * 32 + h4 * 16 + r] = -0.5f * sq;
    }
}

// ---- main: 512 blocks x 256 threads; block = 128 hw rows, wave w owns rows
// w*32..w*32+31 and sweeps all 1024 codes. LDS xt entry E=(ks*2+half)*128+row
// holds x[row][ks*16+half*8 .. +7] as 8 bf16 (16 B).
__global__ __launch_bounds__(256, 2) void vq_main(const float* __restrict__ x,
                                                  const float* __restrict__ cb,
                                                  const bf16x8_t* __restrict__ cbsw,
                                                  const float* __restrict__ nh_ord,
                                                  float* __restrict__ out,
                                                  float* __restrict__ loss_accum) {
    __shared__ uint32_t xt[16 * 2 * 128 * 4];   // 64 KB, B-frag order
    __shared__ int sfin[128];

    const int t     = threadIdx.x;
    const int w     = t >> 6;
    const int lane  = t & 63;
    const int n0    = blockIdx.x * 128;
    const int batch = n0 >> 10;
    const int hw0   = n0 & 1023;

    // ---- stage x -> LDS in fragment order (conflict-free b128 writes) + ||x||^2
    float sqw;
    {
        const int col = t & 127;         // hw row within block
        const int sel = t >> 7;          // 0/1: which d-octet family
        const float* xp = x + (size_t)batch * (DIM * 1024) + hw0 + col;
        float sq = 0.f;
        #pragma unroll
        for (int i = 0; i < 16; ++i) {
            const int d0 = sel * 8 + i * 16;     // 8 consecutive d, one LDS entry
            float a[8];
            #pragma unroll
            for (int j = 0; j < 8; ++j) {
                a[j] = xp[(size_t)(d0 + j) * 1024];
                sq += a[j] * a[j];
            }
            uint4 pk;
            pk.x = f2bf(a[0]) | (f2bf(a[1]) << 16);
            pk.y = f2bf(a[2]) | (f2bf(a[3]) << 16);
            pk.z = f2bf(a[4]) | (f2bf(a[5]) << 16);
            pk.w = f2bf(a[6]) | (f2bf(a[7]) << 16);
            const int ks   = d0 >> 4;
            const int half = (d0 >> 3) & 1;
            *(uint4*)&xt[ks * 1024 + half * 512 + col * 4] = pk;
        }
        // wave-level ||x||^2 partial (256 threads cover every (row,d) once)
        #pragma unroll
        for (int m = 32; m; m >>= 1) sq += __shfl_xor(sq, m);
        sqw = sq;                         // full wave sum, all lanes
    }
    __syncthreads();

    const int half = lane >> 5;
    const int col  = lane & 31;

    // ---- hoist this wave's 16 B-frags into registers: K-loop does no LDS reads
    bf16x8_t breg[16];
    {
        const uint32_t* xb = xt + half * 512 + (w * 32 + col) * 4;
        #pragma unroll
        for (int ks = 0; ks < 16; ++ks)
            breg[ks] = *(const bf16x8_t*)(xb + ks * 1024);
    }

    // ---- K-loop over all 32 m-tiles; A register-pipelined 8 frags deep.
    // All 4 waves read identical cbsw addresses in the same order (L1 dedup).
    const bf16x8_t* apm = cbsw + lane;        // frag for this lane; +64 per ks
    bf16x8_t P0[8], P1[8];
    #pragma unroll
    for (int k = 0; k < 8; ++k) P0[k] = apm[k * 64];    // prologue: mt0 ks0-7

    const f32x4_t* nhp = (const f32x4_t*)(nh_ord + half * 16);
    float best = -3.0e38f;
    int   bi = 0;

    #pragma unroll 1
    for (int mt = 0; mt < 32; ++mt) {
        const f32x4_t nh0 = nhp[0], nh1 = nhp[1], nh2 = nhp[2], nh3 = nhp[3];

        // issue loads for this m-tile's second half (overlap chain0 MFMAs)
        #pragma unroll
        for (int k = 0; k < 8; ++k) P1[k] = apm[(8 + k) * 64];

        f32x16_t c0, c1;
        #pragma unroll
        for (int r = 0; r < 16; ++r) { c0[r] = 0.f; c1[r] = 0.f; }

        #pragma unroll
        for (int k = 0; k < 8; ++k)
            c0 = __builtin_amdgcn_mfma_f32_32x32x16_bf16(P0[k], breg[k], c0, 0, 0, 0);

        // issue loads for next m-tile's first half (overlap chain1 + scan)
        const bf16x8_t* apn = (mt == 31) ? (cbsw + lane) : (apm + 16 * 64);
        #pragma unroll
        for (int k = 0; k < 8; ++k) P0[k] = apn[k * 64];

        #pragma unroll
        for (int k = 0; k < 8; ++k)
            c1 = __builtin_amdgcn_mfma_f32_32x32x16_bf16(P1[k], breg[8 + k], c1, 0, 0, 0);

        // scan: score = dot - 0.5||c||^2 (norm applied here, off the MFMA chain)
        const int cbase = mt * 32 + half * 4;
        #pragma unroll
        for (int r = 0; r < 16; ++r) {
            const float nv = (r < 4) ? nh0[r] : (r < 8) ? nh1[r - 4]
                           : (r < 12) ? nh2[r - 8] : nh3[r - 12];
            const float v = c0[r] + c1[r] + nv;
            const int code = cbase + (r & 3) + 8 * (r >> 2);
            if (v > best) { best = v; bi = code; }
        }
        apm += 16 * 64;
        nhp += 8;
    }

    // ---- combine the two k-half lanes (same hw row, disjoint code subsets)
    {
        const float ov = __shfl_xor(best, 32);
        const int   oi = __shfl_xor(bi, 32);
        if (ov > best || (ov == best && oi < bi)) { best = ov; bi = oi; }
    }
    if (lane < 32) sfin[w * 32 + lane] = bi;

    // ---- per-wave loss partial: lanes and their ^32 twins duplicate each row,
    // so sum of (-best) over 64 lanes = -2*sum_rows(best). Add ||x||^2 partial.
    {
        float ls = -best;
        #pragma unroll
        for (int m = 32; m; m >>= 1) ls += __shfl_xor(ls, m);
        if (lane == 0) atomicAdd(loss_accum, ls + sqw);
    }
    __syncthreads();

    // ---- epilogue: gather fp32 codebook rows, dwordx4 stores along hw
    {
        const int q  = t & 31;     // rows 4q..4q+3
        const int dg = t >> 5;     // 0..7 -> d in [dg*32, dg*32+32)
        const int c0i = sfin[4 * q + 0], c1i = sfin[4 * q + 1];
        const int c2i = sfin[4 * q + 2], c3i = sfin[4 * q + 3];
        const float* r0 = cb + c0i * DIM;
        const float* r1 = cb + c1i * DIM;
        const float* r2 = cb + c2i * DIM;
        const float* r3 = cb + c3i * DIM;
        float* ob = out + (size_t)batch * (DIM * 1024) + hw0 + 4 * q;
        #pragma unroll 4
        for (int j = 0; j < 32; ++j) {
            const int d = dg * 32 + j;
            f32x4_t v; v.x = r0[d]; v.y = r1[d]; v.z = r2[d]; v.w = r3[d];
            *(f32x4_t*)(ob + (size_t)d * 1024) = v;
        }
    }
}

// ---- finalize loss ----
__global__ void vq_final(const float* __restrict__ loss_accum, float* __restrict__ out_loss) {
    *out_loss = 1.25f * (*loss_accum) / 16777216.f;
}

extern "C" void kernel_launch(void* const* d_in, const int* in_sizes, int n_in,
                              void* d_out, int out_size, void* d_ws, size_t ws_size,
                              hipStream_t stream) {
    const float* x  = (const float*)d_in[0];   // [64,256,32,32]
    const float* cb = (const float*)d_in[1];   // [1024,256]
    float* out = (float*)d_out;                // 16777216 + 1

    char* ws = (char*)d_ws;
    float* loss_accum = (float*)ws;                        // 4 B
    char*  cbsw       = ws + 1024;                         // 512 KB, A-frag order
    float* nh_ord     = (float*)(ws + 1024 + 512 * 1024);  // 4 KB

    vq_prep<<<dim3(256), dim3(256), 0, stream>>>(cb, cbsw, nh_ord, loss_accum);
    vq_main<<<dim3(512), dim3(256), 0, stream>>>(x, cb, (const bf16x8_t*)cbsw, nh_ord,
                                                 out, loss_accum);
    vq_final<<<dim3(1), dim3(1), 0, stream>>>(loss_accum, out + 16777216);
}